// Round 11
// baseline (781.406 us; speedup 1.0000x reference)
//
#include <hip/hip_runtime.h>
#include <hip/hip_bf16.h>

// Problem constants
#define BROWS 16384
#define NDIM  2048
#define NCLS  100

typedef __attribute__((ext_vector_type(8))) __bf16 bf16x8;
typedef __attribute__((ext_vector_type(4))) float f32x4;
typedef __attribute__((ext_vector_type(16))) float f32x16;
typedef __attribute__((ext_vector_type(4))) unsigned short u16x4;
typedef __attribute__((ext_vector_type(8))) unsigned short u16x8;

__device__ __forceinline__ unsigned short f2bf(float f) {
    union { float f; unsigned int u; } v; v.f = f;
    unsigned int u = v.u;
    unsigned int r = (u + 0x7fffu + ((u >> 16) & 1u)) >> 16;   // RNE
    return (unsigned short)r;
}
__device__ __forceinline__ float bf2f(unsigned short h) {
    union { unsigned int u; float f; } v; v.u = ((unsigned int)h) << 16;
    return v.f;
}

#define GLOAD_LDS(g, l) \
    __builtin_amdgcn_global_load_lds((const __attribute__((address_space(1))) void*)(g), \
                                     (__attribute__((address_space(3))) void*)(l), 16, 0, 0)

// Raw barrier + counted vmcnt (T4): per-wave drain, then barrier broadcasts.
#define WAITCNT_VM(N) asm volatile("s_waitcnt vmcnt(" #N ")" ::: "memory")
#define WAITCNT_LGKM0() do { \
    asm volatile("s_waitcnt lgkmcnt(0)" ::: "memory"); \
    __builtin_amdgcn_sched_barrier(0); \
} while (0)
#define RAW_BARRIER() __builtin_amdgcn_s_barrier()

// ---------------------------------------------------------------------------
// prep: split x and w into (hi,lo) bf16 pairs; optionally also convert
// fc_weight -> bf16 (hi only) into its own slot (one launch fewer).
// ---------------------------------------------------------------------------
__global__ __launch_bounds__(256) void prep_kernel(const float4* __restrict__ x,
                                                   const float4* __restrict__ w,
                                                   const float4* __restrict__ f,
                                                   u16x4* __restrict__ xhi, u16x4* __restrict__ xlo,
                                                   u16x4* __restrict__ whi, u16x4* __restrict__ wlo,
                                                   u16x4* __restrict__ fdst,
                                                   int n4x, int n4w, int n4f)
{
    int i = blockIdx.x * 256 + threadIdx.x;
    if (i < n4x + n4w) {
        const float4* src; u16x4 *hi, *lo; int idx;
        if (i < n4x) { src = x; hi = xhi; lo = xlo; idx = i; }
        else { idx = i - n4x; src = w; hi = whi; lo = wlo; }
        float4 v = src[idx];
        u16x4 h, l;
        h.x = f2bf(v.x); l.x = f2bf(v.x - bf2f(h.x));
        h.y = f2bf(v.y); l.y = f2bf(v.y - bf2f(h.y));
        h.z = f2bf(v.z); l.z = f2bf(v.z - bf2f(h.z));
        h.w = f2bf(v.w); l.w = f2bf(v.w - bf2f(h.w));
        hi[idx] = h; lo[idx] = l;
    } else if (fdst != nullptr) {
        int idx = i - n4x - n4w;
        if (idx >= n4f) return;
        float4 v = f[idx];
        u16x4 h;
        h.x = f2bf(v.x); h.y = f2bf(v.y); h.z = f2bf(v.z); h.w = f2bf(v.w);
        fdst[idx] = h;
    }
}

// fp32 -> bf16 (hi only) — fallback (small-ws) path only.
__global__ __launch_bounds__(256) void cvt_bf16_kernel(const float4* __restrict__ src,
                                                       u16x4* __restrict__ dst, int n4)
{
    int i = blockIdx.x * 256 + threadIdx.x;
    if (i >= n4) return;
    float4 v = src[i];
    u16x4 h;
    h.x = f2bf(v.x); h.y = f2bf(v.y); h.z = f2bf(v.z); h.w = f2bf(v.w);
    dst[i] = h;
}

// ---------------------------------------------------------------------------
// GEMM1 (MFMA 32x32x16, split-bf16, fused) — R15: 256x256 / BK=32 / 4-phase.
// C = Xhi.Whi + Xhi.Wlo + Xlo.Whi + bias.
// Rationale: split-bf16 carries 4 staged tensors, so the m201 256x256/BK=64
// geometry needs ~256 KB LDS (infeasible) — but BK=32 fits: 4 x 16 KB x
// 2 buffers = 128 KB. vs the 128x256 plateau config this doubles FLOP per
// staged byte and cuts ds_reads/MFMA from 8/12 to ~6/12 (B-frags read once
// per ks, reused across the i-pair phases). 512 thr / 8 waves (2x4 wave
// grid), per-wave output 128x64, acc = 128 f32/lane (m201 occupancy regime:
// 2 waves/SIMD, latency covered by the phase pipeline, not TLP).
// Per K-tile, 4 phases {ds_reads ; gloads ; barrier ; lgkm0+sched_bar ;
// setprio ; 12 MFMA ; setprio ; barrier}; all 8 next-tile gloads issued in
// phases A/B; single vmcnt(0) at phase D (~2.5 phases of issue->wait cover;
// dbuf forces the drain, cover distance is what matters).
// Precision: 3 MFMA passes REQUIRED (cross-term omission -> ~0.3-knot
// interp position errors -> fails tolerance).
// ---------------------------------------------------------------------------
__global__ __launch_bounds__(512) void gemm1_mfma_fused_kernel(
        const unsigned short* __restrict__ xhi,
        const unsigned short* __restrict__ xlo,
        const unsigned short* __restrict__ whi,
        const unsigned short* __restrict__ wlo,
        const float* __restrict__ bias,
        float* __restrict__ C)
{
    __shared__ unsigned short sAh[2 * 256 * 32];   // 32 KB each
    __shared__ unsigned short sAl[2 * 256 * 32];
    __shared__ unsigned short sBh[2 * 256 * 32];
    __shared__ unsigned short sBl[2 * 256 * 32];   // total 128 KB

    const int tid  = threadIdx.x;    // 0..511
    const int lane = tid & 63;
    const int w    = tid >> 6;       // 0..7
    const int wm   = w >> 2;         // 0..1: m-half (128 rows)
    const int wn   = w & 3;          // 0..3: n-quarter (64 cols)
    const int m0   = blockIdx.y * 256;
    const int n0   = blockIdx.x * 256;

    // staging: per tensor 1024 chunks (256 rows x 4 chunks of 8 bf16); 2/thread
    size_t a_goff[2], b_goff[2]; int lb[2];
#pragma unroll
    for (int t = 0; t < 2; t++) {
        const int c = t * 512 + tid;
        const int r = c >> 2;
        const int q = (c & 3) ^ ((r >> 1) & 3);
        a_goff[t] = (size_t)(m0 + r) * NDIM + q * 8;
        b_goff[t] = (size_t)(n0 + r) * NDIM + q * 8;
        lb[t] = (t * 512 + w * 64) * 8;   // wave-uniform base (shorts)
    }

    // fragment read offsets: frag row r, logical k-chunk q = 2*ks + lk2
    const int ln32 = lane & 31;
    const int lk2  = lane >> 5;
    int offA[4][2], offB[2][2];   // [tile][ks]
#pragma unroll
    for (int i = 0; i < 4; i++)
#pragma unroll
        for (int ks = 0; ks < 2; ks++) {
            const int rfa = wm * 128 + i * 32 + ln32;
            offA[i][ks] = rfa * 32 + (((2 * ks + lk2) ^ ((rfa >> 1) & 3)) * 8);
        }
#pragma unroll
    for (int j = 0; j < 2; j++)
#pragma unroll
        for (int ks = 0; ks < 2; ks++) {
            const int rfb = wn * 64 + j * 32 + ln32;
            offB[j][ks] = rfb * 32 + (((2 * ks + lk2) ^ ((rfb >> 1) & 3)) * 8);
        }

    f32x16 acc[4][2];
#pragma unroll
    for (int i = 0; i < 4; i++)
#pragma unroll
        for (int j = 0; j < 2; j++)
#pragma unroll
            for (int r = 0; r < 16; r++) acc[i][j][r] = 0.f;

#define G1_STAGE_A(SB, KT) do { \
    GLOAD_LDS(xhi + a_goff[0] + (KT), &sAh[(SB) + lb[0]]); \
    GLOAD_LDS(xhi + a_goff[1] + (KT), &sAh[(SB) + lb[1]]); \
    GLOAD_LDS(xlo + a_goff[0] + (KT), &sAl[(SB) + lb[0]]); \
    GLOAD_LDS(xlo + a_goff[1] + (KT), &sAl[(SB) + lb[1]]); \
} while (0)
#define G1_STAGE_B(SB, KT) do { \
    GLOAD_LDS(whi + b_goff[0] + (KT), &sBh[(SB) + lb[0]]); \
    GLOAD_LDS(whi + b_goff[1] + (KT), &sBh[(SB) + lb[1]]); \
    GLOAD_LDS(wlo + b_goff[0] + (KT), &sBl[(SB) + lb[0]]); \
    GLOAD_LDS(wlo + b_goff[1] + (KT), &sBl[(SB) + lb[1]]); \
} while (0)

#define MFMA3(ACC, AH, AL, BH, BL) do { \
    ACC = __builtin_amdgcn_mfma_f32_32x32x16_bf16(AH, BH, ACC, 0, 0, 0); \
    ACC = __builtin_amdgcn_mfma_f32_32x32x16_bf16(AH, BL, ACC, 0, 0, 0); \
    ACC = __builtin_amdgcn_mfma_f32_32x32x16_bf16(AL, BH, ACC, 0, 0, 0); \
} while (0)

    // prologue: tile 0 -> buf 0 (8 loads), drain, barrier
    G1_STAGE_A(0, 0);
    G1_STAGE_B(0, 0);
    WAITCNT_VM(0);
    RAW_BARRIER();

    int cb = 0;   // compute-buffer offset (shorts); stage buffer = cb ^ 8192
    for (int kt = 0; kt < NDIM; kt += 32) {
        const int skt = (kt + 32 < NDIM) ? kt + 32 : 0;   // dummy on last iter
        const int sb = cb ^ 8192;

        // ---------------- ks = 0 ----------------
        {
            bf16x8 bh0 = *(const bf16x8*)&sBh[cb + offB[0][0]];
            bf16x8 bh1 = *(const bf16x8*)&sBh[cb + offB[1][0]];
            bf16x8 bl0 = *(const bf16x8*)&sBl[cb + offB[0][0]];
            bf16x8 bl1 = *(const bf16x8*)&sBl[cb + offB[1][0]];
            // phase A: i = 0,1 ; stage next-tile A (4 gloads)
            {
                bf16x8 ah0 = *(const bf16x8*)&sAh[cb + offA[0][0]];
                bf16x8 ah1 = *(const bf16x8*)&sAh[cb + offA[1][0]];
                bf16x8 al0 = *(const bf16x8*)&sAl[cb + offA[0][0]];
                bf16x8 al1 = *(const bf16x8*)&sAl[cb + offA[1][0]];
                G1_STAGE_A(sb, skt);
                RAW_BARRIER();
                WAITCNT_LGKM0();
                __builtin_amdgcn_s_setprio(1);
                MFMA3(acc[0][0], ah0, al0, bh0, bl0);
                MFMA3(acc[0][1], ah0, al0, bh1, bl1);
                MFMA3(acc[1][0], ah1, al1, bh0, bl0);
                MFMA3(acc[1][1], ah1, al1, bh1, bl1);
                __builtin_amdgcn_s_setprio(0);
                RAW_BARRIER();
            }
            // phase B: i = 2,3 (reuse B frags) ; stage next-tile B (4 gloads)
            {
                bf16x8 ah2 = *(const bf16x8*)&sAh[cb + offA[2][0]];
                bf16x8 ah3 = *(const bf16x8*)&sAh[cb + offA[3][0]];
                bf16x8 al2 = *(const bf16x8*)&sAl[cb + offA[2][0]];
                bf16x8 al3 = *(const bf16x8*)&sAl[cb + offA[3][0]];
                G1_STAGE_B(sb, skt);
                RAW_BARRIER();
                WAITCNT_LGKM0();
                __builtin_amdgcn_s_setprio(1);
                MFMA3(acc[2][0], ah2, al2, bh0, bl0);
                MFMA3(acc[2][1], ah2, al2, bh1, bl1);
                MFMA3(acc[3][0], ah3, al3, bh0, bl0);
                MFMA3(acc[3][1], ah3, al3, bh1, bl1);
                __builtin_amdgcn_s_setprio(0);
                RAW_BARRIER();
            }
        }
        // ---------------- ks = 1 ----------------
        {
            bf16x8 bh0 = *(const bf16x8*)&sBh[cb + offB[0][1]];
            bf16x8 bh1 = *(const bf16x8*)&sBh[cb + offB[1][1]];
            bf16x8 bl0 = *(const bf16x8*)&sBl[cb + offB[0][1]];
            bf16x8 bl1 = *(const bf16x8*)&sBl[cb + offB[1][1]];
            // phase C: i = 0,1 (no gloads)
            {
                bf16x8 ah0 = *(const bf16x8*)&sAh[cb + offA[0][1]];
                bf16x8 ah1 = *(const bf16x8*)&sAh[cb + offA[1][1]];
                bf16x8 al0 = *(const bf16x8*)&sAl[cb + offA[0][1]];
                bf16x8 al1 = *(const bf16x8*)&sAl[cb + offA[1][1]];
                RAW_BARRIER();
                WAITCNT_LGKM0();
                __builtin_amdgcn_s_setprio(1);
                MFMA3(acc[0][0], ah0, al0, bh0, bl0);
                MFMA3(acc[0][1], ah0, al0, bh1, bl1);
                MFMA3(acc[1][0], ah1, al1, bh0, bl0);
                MFMA3(acc[1][1], ah1, al1, bh1, bl1);
                __builtin_amdgcn_s_setprio(0);
                RAW_BARRIER();
            }
            // phase D: i = 2,3 ; vmcnt(0) -> next tile fully landed
            {
                bf16x8 ah2 = *(const bf16x8*)&sAh[cb + offA[2][1]];
                bf16x8 ah3 = *(const bf16x8*)&sAh[cb + offA[3][1]];
                bf16x8 al2 = *(const bf16x8*)&sAl[cb + offA[2][1]];
                bf16x8 al3 = *(const bf16x8*)&sAl[cb + offA[3][1]];
                WAITCNT_VM(0);
                RAW_BARRIER();
                WAITCNT_LGKM0();
                __builtin_amdgcn_s_setprio(1);
                MFMA3(acc[2][0], ah2, al2, bh0, bl0);
                MFMA3(acc[2][1], ah2, al2, bh1, bl1);
                MFMA3(acc[3][0], ah3, al3, bh0, bl0);
                MFMA3(acc[3][1], ah3, al3, bh1, bl1);
                __builtin_amdgcn_s_setprio(0);
                RAW_BARRIER();
            }
        }
        cb = sb;
    }

#undef G1_STAGE_A
#undef G1_STAGE_B
#undef MFMA3

    // epilogue: 32x32 C/D: col = lane&31, row = (reg&3)+8*(reg>>2)+4*(lane>>5)
    float bb[2];
#pragma unroll
    for (int j = 0; j < 2; j++) bb[j] = bias[n0 + wn * 64 + j * 32 + ln32];
#pragma unroll
    for (int i = 0; i < 4; i++) {
#pragma unroll
        for (int j = 0; j < 2; j++) {
            const int n = n0 + wn * 64 + j * 32 + ln32;
#pragma unroll
            for (int reg = 0; reg < 16; reg++) {
                const int m = m0 + wm * 128 + i * 32 + (reg & 3) + 8 * (reg >> 2) + 4 * lk2;
                C[(size_t)m * NDIM + n] = acc[i][j][reg] + bb[j];
            }
        }
    }
}

// ---------------------------------------------------------------------------
// Warp kernel — R5 VERBATIM. Reads x~ = xhi+xlo (L2/L3-warm from gemm1's
// sweeps; R8 showed reading cold fp32 x costs ~30us despite same byte count).
// gamma = cumsum(softmax(row)); warped = interp(gamma, xs, x~).
// Padded s_x index i+(i>>5) breaks the interp-gather bank conflict.
// Self-aliasing (Wout == xlo) safe: each thread overwrites only its own 16B.
// ---------------------------------------------------------------------------
#define SXI(i) ((i) + ((i) >> 5))

__global__ __launch_bounds__(256) void warp_bf16_kernel(const unsigned short* __restrict__ Xhi,
                                                        const unsigned short* __restrict__ Xlo,
                                                        const float* __restrict__ L,
                                                        unsigned short* __restrict__ Wout)
{
    const int N = NDIM;
    const int row = blockIdx.x;
    const int tid = threadIdx.x;
    const int lane = tid & 63;
    const int wave = tid >> 6;

    __shared__ float s_x[NDIM + NDIM / 32];   // padded: 1 extra per 32
    __shared__ float s_red[4];
    __shared__ float s_wsum[4];

    const float* lrow = L + (size_t)row * N;

    float v[8];
    {
        float4 l0 = *(const float4*)(lrow + tid * 8);
        float4 l1 = *(const float4*)(lrow + tid * 8 + 4);
        v[0] = l0.x; v[1] = l0.y; v[2] = l0.z; v[3] = l0.w;
        v[4] = l1.x; v[5] = l1.y; v[6] = l1.z; v[7] = l1.w;
        u16x8 hx = *(const u16x8*)(Xhi + (size_t)row * N + tid * 8);
        u16x8 lx = *(const u16x8*)(Xlo + (size_t)row * N + tid * 8);
        float xv[8];
#pragma unroll
        for (int j = 0; j < 8; j++) xv[j] = bf2f(hx[j]) + bf2f(lx[j]);
        const int sb = SXI(tid * 8);   // 8 consecutive slots share the shift
        *(float4*)&s_x[sb]     = make_float4(xv[0], xv[1], xv[2], xv[3]);
        *(float4*)&s_x[sb + 4] = make_float4(xv[4], xv[5], xv[6], xv[7]);
    }

    float mx = v[0];
#pragma unroll
    for (int j = 1; j < 8; j++) mx = fmaxf(mx, v[j]);
#pragma unroll
    for (int off = 32; off > 0; off >>= 1) mx = fmaxf(mx, __shfl_down(mx, off));
    if (lane == 0) s_red[wave] = mx;
    __syncthreads();
    mx = fmaxf(fmaxf(s_red[0], s_red[1]), fmaxf(s_red[2], s_red[3]));

    float c = 0.0f;
#pragma unroll
    for (int j = 0; j < 8; j++) {
        float e = __expf(v[j] - mx);
        c += e;
        v[j] = c;
    }

    float sc = c;
#pragma unroll
    for (int off = 1; off < 64; off <<= 1) {
        float t = __shfl_up(sc, off);
        if (lane >= off) sc += t;
    }
    if (lane == 63) s_wsum[wave] = sc;
    __syncthreads();
    float base = 0.0f, total = 0.0f;
#pragma unroll
    for (int w = 0; w < 4; w++) {
        float t = s_wsum[w];
        if (w < wave) base += t;
        total += t;
    }
    const float inv = 1.0f / total;
    const float prefix = base + (sc - c);

    u16x8 o;
#pragma unroll
    for (int j = 0; j < 8; j++) {
        float g = (prefix + v[j]) * inv;
        float pos = g * (float)(N - 1);
        pos = fminf(fmaxf(pos, 0.0f), (float)(N - 1));
        int i = (int)pos;
        if (i > N - 2) i = N - 2;
        float f = pos - (float)i;
        float x0 = s_x[SXI(i)];
        float x1 = s_x[SXI(i + 1)];
        o[j] = f2bf(fmaf(f, x1 - x0, x0));
    }
    *(u16x8*)(Wout + (size_t)row * N + tid * 8) = o;
}

// ---------------------------------------------------------------------------
// GEMM2 (MFMA bf16) — R5 VERBATIM (proven best):
// out[m][n] = sum_k Wp[m][k]*F[n][k] + fb[n]  (n<100)
// BM=32 (grid 512 -> 2 blocks/CU), BN=128 (rows>=100 clamped), 4 waves each
// owning 32x32. LDS 40 KB double-buffered; counted vmcnt(5).
// ---------------------------------------------------------------------------
__global__ __launch_bounds__(256) void gemm2_mfma_kernel(
        const unsigned short* __restrict__ Wp,   // warped bf16 [16384][2048]
        const unsigned short* __restrict__ F,    // fc bf16 [100][2048]
        const float* __restrict__ fb,
        float* __restrict__ out)
{
    __shared__ unsigned short sA[2 * 32 * 64];    // 8 KB, [r][q'] 8 chunks/row
    __shared__ unsigned short sB[2 * 128 * 64];   // 32 KB

    const int tid  = threadIdx.x;
    const int lane = tid & 63;
    const int w    = tid >> 6;   // wave owns n-strip w*32 .. +32
    const int m0   = blockIdx.x * 32;

    // A staging: 256 chunks (32 rows x 8), 1/thread; lane order = r*8+q
    const int ar = tid >> 3, aq = tid & 7;
    const size_t a_goff = (size_t)(m0 + ar) * NDIM + ((aq ^ (ar & 7)) * 8);
    const int a_lb = (w * 64) * 8;   // wave-uniform base (shorts)

    // B staging: 1024 chunks (128 rows x 8), 4/thread; fc row clamped to 99
    size_t b_goff[4]; int b_lb[4];
#pragma unroll
    for (int t = 0; t < 4; t++) {
        const int c = t * 256 + tid;
        const int r = c >> 3, q = c & 7;
        b_goff[t] = (size_t)(r < NCLS ? r : NCLS - 1) * NDIM + ((q ^ (r & 7)) * 8);
        b_lb[t]   = (t * 256 + w * 64) * 8;
    }

    // fragment offsets (16x16x32): logical k-chunk = ks*4 + (lane>>4)
    const int lm = lane & 15;
    const int lk = lane >> 4;
    int offA[2][2], offB[2][2];
#pragma unroll
    for (int i = 0; i < 2; i++)
#pragma unroll
        for (int ks = 0; ks < 2; ks++) {
            const int r = i * 16 + lm;                 // A rows 0..31 (all waves)
            offA[i][ks] = (r * 8 + ((ks * 4 + lk) ^ (r & 7))) * 8;
            const int rb = w * 32 + i * 16 + lm;       // B rows per wave strip
            offB[i][ks] = (rb * 8 + ((ks * 4 + lk) ^ (rb & 7))) * 8;
        }

    f32x4 acc[2][2];
#pragma unroll
    for (int i = 0; i < 2; i++)
#pragma unroll
        for (int j = 0; j < 2; j++) acc[i][j] = (f32x4){0.f, 0.f, 0.f, 0.f};

#define G2_STAGE(B, KT) do { \
    GLOAD_LDS(Wp + a_goff + (KT), &sA[(B) * 2048 + a_lb]); \
    _Pragma("unroll") \
    for (int t = 0; t < 4; t++) GLOAD_LDS(F + b_goff[t] + (KT), &sB[(B) * 8192 + b_lb[t]]); \
} while (0)

#define G2_COMPUTE(B) do { \
    _Pragma("unroll") \
    for (int ks = 0; ks < 2; ks++) { \
        bf16x8 af[2], bfr[2]; \
        _Pragma("unroll") \
        for (int i = 0; i < 2; i++) { \
            af[i]  = *(const bf16x8*)&sA[(B) * 2048 + offA[i][ks]]; \
            bfr[i] = *(const bf16x8*)&sB[(B) * 8192 + offB[i][ks]]; \
        } \
        _Pragma("unroll") \
        for (int i = 0; i < 2; i++) \
            _Pragma("unroll") \
            for (int j = 0; j < 2; j++) \
                acc[i][j] = __builtin_amdgcn_mfma_f32_16x16x32_bf16(af[i], bfr[j], acc[i][j], 0, 0, 0); \
    } \
} while (0)

    G2_STAGE(0, 0);   // 5 loads in flight

    for (int kt = 0; kt < NDIM; kt += 128) {
        G2_STAGE(1, kt + 64);            // +5 (kt+64 <= 1984, always valid)
        WAITCNT_VM(5);                   // buf0's 5 landed; buf1's stay in flight
        RAW_BARRIER();
        G2_COMPUTE(0);
        RAW_BARRIER();
        G2_STAGE(0, (kt + 128 < NDIM) ? kt + 128 : 0);   // dummy on last iter
        WAITCNT_VM(5);
        RAW_BARRIER();
        G2_COMPUTE(1);
        RAW_BARRIER();
    }

#undef G2_STAGE
#undef G2_COMPUTE

    const int cn = lane & 15;
    const int rg = lane >> 4;
#pragma unroll
    for (int i = 0; i < 2; i++) {
#pragma unroll
        for (int j = 0; j < 2; j++) {
            const int n = w * 32 + j * 16 + cn;
            if (n < NCLS) {
                const float bbn = fb[n];
#pragma unroll
                for (int reg = 0; reg < 4; reg++) {
                    const int m = m0 + i * 16 + rg * 4 + reg;
                    out[(size_t)m * NCLS + n] = acc[i][j][reg] + bbn;
                }
            }
        }
    }
}

// ---------------------------------------------------------------------------
// fp32 fallback path (only if ws_size too small) — proven R1 kernels.
// ---------------------------------------------------------------------------
__global__ __launch_bounds__(256) void gemm1_kernel(const float* __restrict__ X,
                                                    const float* __restrict__ W,
                                                    const float* __restrict__ bias,
                                                    float* __restrict__ C)
{
    const int K = NDIM;
    __shared__ float sA[16][128];
    __shared__ float sB[16][128];
    const int tid = threadIdx.x;
    const int tx = tid & 15;
    const int ty = tid >> 4;
    const int m0 = blockIdx.y * 128;
    const int n0 = blockIdx.x * 128;
    float acc[8][8];
#pragma unroll
    for (int i = 0; i < 8; i++)
#pragma unroll
        for (int j = 0; j < 8; j++) acc[i][j] = 0.0f;
    const int s_m = tid >> 1;
    const int s_c = (tid & 1) * 8;
    const float* Ag = X + (size_t)(m0 + s_m) * K + s_c;
    const float* Bg = W + (size_t)(n0 + s_m) * K + s_c;
    for (int kt = 0; kt < K; kt += 16) {
        float4 av0 = *(const float4*)(Ag + kt);
        float4 av1 = *(const float4*)(Ag + kt + 4);
        float4 bv0 = *(const float4*)(Bg + kt);
        float4 bv1 = *(const float4*)(Bg + kt + 4);
        __syncthreads();
        sA[s_c + 0][s_m] = av0.x; sA[s_c + 1][s_m] = av0.y;
        sA[s_c + 2][s_m] = av0.z; sA[s_c + 3][s_m] = av0.w;
        sA[s_c + 4][s_m] = av1.x; sA[s_c + 5][s_m] = av1.y;
        sA[s_c + 6][s_m] = av1.z; sA[s_c + 7][s_m] = av1.w;
        sB[s_c + 0][s_m] = bv0.x; sB[s_c + 1][s_m] = bv0.y;
        sB[s_c + 2][s_m] = bv0.z; sB[s_c + 3][s_m] = bv0.w;
        sB[s_c + 4][s_m] = bv1.x; sB[s_c + 5][s_m] = bv1.y;
        sB[s_c + 6][s_m] = bv1.z; sB[s_c + 7][s_m] = bv1.w;
        __syncthreads();
#pragma unroll
        for (int k = 0; k < 16; k++) {
            float4 a0 = *(const float4*)&sA[k][ty * 8];
            float4 a1 = *(const float4*)&sA[k][ty * 8 + 4];
            float4 b0 = *(const float4*)&sB[k][tx * 8];
            float4 b1 = *(const float4*)&sB[k][tx * 8 + 4];
            float a[8] = {a0.x, a0.y, a0.z, a0.w, a1.x, a1.y, a1.z, a1.w};
            float b[8] = {b0.x, b0.y, b0.z, b0.w, b1.x, b1.y, b1.z, b1.w};
#pragma unroll
            for (int i = 0; i < 8; i++)
#pragma unroll
                for (int j = 0; j < 8; j++)
                    acc[i][j] = fmaf(a[i], b[j], acc[i][j]);
        }
    }
    float bb[8];
#pragma unroll
    for (int j = 0; j < 8; j++) bb[j] = bias[n0 + tx * 8 + j];
#pragma unroll
    for (int i = 0; i < 8; i++) {
        const int m = m0 + ty * 8 + i;
        float* crow = C + (size_t)m * NDIM + n0 + tx * 8;
        *(float4*)(crow)     = make_float4(acc[i][0] + bb[0], acc[i][1] + bb[1],
                                           acc[i][2] + bb[2], acc[i][3] + bb[3]);
        *(float4*)(crow + 4) = make_float4(acc[i][4] + bb[4], acc[i][5] + bb[5],
                                           acc[i][6] + bb[6], acc[i][7] + bb[7]);
    }
}

__global__ __launch_bounds__(256) void warp_kernel_f32(const float* __restrict__ X,
                                                       float* __restrict__ L)
{
    const int N = NDIM;
    const int row = blockIdx.x;
    const int tid = threadIdx.x;
    const int lane = tid & 63;
    const int wave = tid >> 6;
    __shared__ float s_x[NDIM];
    __shared__ float s_red[4];
    __shared__ float s_wsum[4];
    float* lrow = L + (size_t)row * N;
    const float* xrow = X + (size_t)row * N;
    float v[8];
    {
        float4 l0 = *(const float4*)(lrow + tid * 8);
        float4 l1 = *(const float4*)(lrow + tid * 8 + 4);
        v[0] = l0.x; v[1] = l0.y; v[2] = l0.z; v[3] = l0.w;
        v[4] = l1.x; v[5] = l1.y; v[6] = l1.z; v[7] = l1.w;
        float4 x0 = *(const float4*)(xrow + tid * 8);
        float4 x1 = *(const float4*)(xrow + tid * 8 + 4);
        *(float4*)&s_x[tid * 8]     = x0;
        *(float4*)&s_x[tid * 8 + 4] = x1;
    }
    float mx = v[0];
#pragma unroll
    for (int j = 1; j < 8; j++) mx = fmaxf(mx, v[j]);
#pragma unroll
    for (int off = 32; off > 0; off >>= 1) mx = fmaxf(mx, __shfl_down(mx, off));
    if (lane == 0) s_red[wave] = mx;
    __syncthreads();
    mx = fmaxf(fmaxf(s_red[0], s_red[1]), fmaxf(s_red[2], s_red[3]));
    float c = 0.0f;
#pragma unroll
    for (int j = 0; j < 8; j++) {
        float e = __expf(v[j] - mx);
        c += e;
        v[j] = c;
    }
    float sc = c;
#pragma unroll
    for (int off = 1; off < 64; off <<= 1) {
        float t = __shfl_up(sc, off);
        if (lane >= off) sc += t;
    }
    if (lane == 63) s_wsum[wave] = sc;
    __syncthreads();
    float base = 0.0f, total = 0.0f;
#pragma unroll
    for (int w = 0; w < 4; w++) {
        float t = s_wsum[w];
        if (w < wave) base += t;
        total += t;
    }
    const float inv = 1.0f / total;
    const float prefix = base + (sc - c);
    float w8[8];
#pragma unroll
    for (int j = 0; j < 8; j++) {
        float g = (prefix + v[j]) * inv;
        float pos = g * (float)(N - 1);
        pos = fminf(fmaxf(pos, 0.0f), (float)(N - 1));
        int i = (int)pos;
        if (i > N - 2) i = N - 2;
        float f = pos - (float)i;
        w8[j] = fmaf(f, s_x[i + 1] - s_x[i], s_x[i]);
    }
    *(float4*)(lrow + tid * 8)     = make_float4(w8[0], w8[1], w8[2], w8[3]);
    *(float4*)(lrow + tid * 8 + 4) = make_float4(w8[4], w8[5], w8[6], w8[7]);
}

__global__ __launch_bounds__(256) void gemm2_kernel(const float* __restrict__ Wp,
                                                    const float* __restrict__ F,
                                                    const float* __restrict__ fb,
                                                    float* __restrict__ out)
{
    const int K = NDIM;
    __shared__ float sA[16][64];
    __shared__ float sB[16][128];
    const int tid = threadIdx.x;
    const int tx = tid & 15;
    const int ty = tid >> 4;
    const int m0 = blockIdx.x * 64;
    float acc[4][8];
#pragma unroll
    for (int i = 0; i < 4; i++)
#pragma unroll
        for (int j = 0; j < 8; j++) acc[i][j] = 0.0f;
    const int a_m = tid >> 2;
    const int a_c = (tid & 3) * 4;
    const int b_n = tid >> 1;
    const int b_c = (tid & 1) * 8;
    const bool bvalid = (b_n < NCLS);
    const float* Ag = Wp + (size_t)(m0 + a_m) * K + a_c;
    const float* Bg = F + (size_t)b_n * K + b_c;
    for (int kt = 0; kt < K; kt += 16) {
        float4 av = *(const float4*)(Ag + kt);
        float4 bv0 = make_float4(0.f, 0.f, 0.f, 0.f);
        float4 bv1 = make_float4(0.f, 0.f, 0.f, 0.f);
        if (bvalid) {
            bv0 = *(const float4*)(Bg + kt);
            bv1 = *(const float4*)(Bg + kt + 4);
        }
        __syncthreads();
        sA[a_c + 0][a_m] = av.x; sA[a_c + 1][a_m] = av.y;
        sA[a_c + 2][a_m] = av.z; sA[a_c + 3][a_m] = av.w;
        sB[b_c + 0][b_n] = bv0.x; sB[b_c + 1][b_n] = bv0.y;
        sB[b_c + 2][b_n] = bv0.z; sB[b_c + 3][b_n] = bv0.w;
        sB[b_c + 4][b_n] = bv1.x; sB[b_c + 5][b_n] = bv1.y;
        sB[b_c + 6][b_n] = bv1.z; sB[b_c + 7][b_n] = bv1.w;
        __syncthreads();
#pragma unroll
        for (int k = 0; k < 16; k++) {
            float4 a4 = *(const float4*)&sA[k][ty * 4];
            float4 b0 = *(const float4*)&sB[k][tx * 8];
            float4 b1 = *(const float4*)&sB[k][tx * 8 + 4];
            float a[4] = {a4.x, a4.y, a4.z, a4.w};
            float b[8] = {b0.x, b0.y, b0.z, b0.w, b1.x, b1.y, b1.z, b1.w};
#pragma unroll
            for (int i = 0; i < 4; i++)
#pragma unroll
                for (int j = 0; j < 8; j++)
                    acc[i][j] = fmaf(a[i], b[j], acc[i][j]);
        }
    }
#pragma unroll
    for (int i = 0; i < 4; i++) {
        const int m = m0 + ty * 4 + i;
#pragma unroll
        for (int j = 0; j < 8; j++) {
            const int n = tx * 8 + j;
            if (n < NCLS) out[(size_t)m * NCLS + n] = acc[i][j] + fb[n];
        }
    }
}

extern "C" void kernel_launch(void* const* d_in, const int* in_sizes, int n_in,
                              void* d_out, int out_size, void* d_ws, size_t ws_size,
                              hipStream_t stream) {
    const float* x  = (const float*)d_in[0];   // time_series [16384,2048]
    const float* ww = (const float*)d_in[1];   // w_weight [2048,2048]
    const float* wb = (const float*)d_in[2];   // w_bias [2048]
    const float* fw = (const float*)d_in[3];   // fc_weight [100,2048]
    const float* fb = (const float*)d_in[4];   // fc_bias [100]
    float* out = (float*)d_out;                // [16384,100]

    char* ws = (char*)d_ws;
    float* logits = (float*)ws;                                   // 128 MiB fp32
    const size_t LOGITS_B = (size_t)BROWS * NDIM * 4;             // 134217728
    const size_t XBF_B    = (size_t)BROWS * NDIM * 2;             // 67108864
    const size_t WBF_B    = (size_t)NDIM * NDIM * 2;              // 8388608
    const size_t FCB_B    = (size_t)NCLS * NDIM * 2;              // 409600
    unsigned short* xhi = (unsigned short*)(ws + LOGITS_B);
    unsigned short* xlo = (unsigned short*)(ws + LOGITS_B + XBF_B);
    unsigned short* whi = (unsigned short*)(ws + LOGITS_B + 2 * XBF_B);
    unsigned short* wlo = (unsigned short*)(ws + LOGITS_B + 2 * XBF_B + WBF_B);
    unsigned short* fcb = (unsigned short*)(ws + LOGITS_B + 2 * XBF_B + 2 * WBF_B);
    // alias (dead after gemm1): warped bf16 reuses xlo
    unsigned short* wbf = xlo;
    const size_t WS_NEED  = LOGITS_B + 2 * XBF_B + 2 * WBF_B;     // 285212672
    const size_t WS_NEED2 = WS_NEED + FCB_B;                      // +fc slot

    const int n4x = BROWS * NDIM / 4;   // 8388608
    const int n4w = NDIM * NDIM / 4;    // 1048576
    const int n4f = NCLS * NDIM / 4;    // 51200

    if (ws_size >= WS_NEED2) {
        // main path: prep also converts fc (own slot, no aliasing), 4 launches.
        prep_kernel<<<(n4x + n4w + n4f + 255) / 256, 256, 0, stream>>>(
            (const float4*)x, (const float4*)ww, (const float4*)fw,
            (u16x4*)xhi, (u16x4*)xlo, (u16x4*)whi, (u16x4*)wlo, (u16x4*)fcb,
            n4x, n4w, n4f);
        gemm1_mfma_fused_kernel<<<dim3(NDIM / 256, BROWS / 256), 512, 0, stream>>>(
            xhi, xlo, whi, wlo, wb, logits);
        warp_bf16_kernel<<<BROWS, 256, 0, stream>>>(xhi, xlo, logits, wbf);
        gemm2_mfma_kernel<<<BROWS / 32, 256, 0, stream>>>(wbf, fcb, fb, out);
    } else if (ws_size >= WS_NEED) {
        // smaller-ws path: fc bf16 aliases wlo (must run after gemm1).
        unsigned short* fwb = wlo;
        prep_kernel<<<(n4x + n4w + 255) / 256, 256, 0, stream>>>(
            (const float4*)x, (const float4*)ww, (const float4*)fw,
            (u16x4*)xhi, (u16x4*)xlo, (u16x4*)whi, (u16x4*)wlo, (u16x4*)nullptr,
            n4x, n4w, 0);
        gemm1_mfma_fused_kernel<<<dim3(NDIM / 256, BROWS / 256), 512, 0, stream>>>(
            xhi, xlo, whi, wlo, wb, logits);
        warp_bf16_kernel<<<BROWS, 256, 0, stream>>>(xhi, xlo, logits, wbf);
        cvt_bf16_kernel<<<(n4f + 255) / 256, 256, 0, stream>>>(
            (const float4*)fw, (u16x4*)fwb, n4f);
        gemm2_mfma_kernel<<<BROWS / 32, 256, 0, stream>>>(wbf, fwb, fb, out);
    } else {
        gemm1_kernel<<<dim3(NDIM / 128, BROWS / 128), 256, 0, stream>>>(x, ww, wb, logits);
        warp_kernel_f32<<<BROWS, 256, 0, stream>>>(x, logits);
        gemm2_kernel<<<BROWS / 64, 256, 0, stream>>>(logits, fw, fb, out);
    }
}

// Round 12
// 659.843 us; speedup vs baseline: 1.1842x; 1.1842x over previous
//
#include <hip/hip_runtime.h>
#include <hip/hip_bf16.h>

// Problem constants
#define BROWS 16384
#define NDIM  2048
#define NCLS  100

typedef __attribute__((ext_vector_type(8))) __bf16 bf16x8;
typedef __attribute__((ext_vector_type(4))) float f32x4;
typedef __attribute__((ext_vector_type(16))) float f32x16;
typedef __attribute__((ext_vector_type(4))) unsigned short u16x4;
typedef __attribute__((ext_vector_type(8))) unsigned short u16x8;

__device__ __forceinline__ unsigned short f2bf(float f) {
    union { float f; unsigned int u; } v; v.f = f;
    unsigned int u = v.u;
    unsigned int r = (u + 0x7fffu + ((u >> 16) & 1u)) >> 16;   // RNE
    return (unsigned short)r;
}
__device__ __forceinline__ float bf2f(unsigned short h) {
    union { unsigned int u; float f; } v; v.u = ((unsigned int)h) << 16;
    return v.f;
}

#define GLOAD_LDS(g, l) \
    __builtin_amdgcn_global_load_lds((const __attribute__((address_space(1))) void*)(g), \
                                     (__attribute__((address_space(3))) void*)(l), 16, 0, 0)

// Raw barrier + counted vmcnt (T4): per-wave drain to N, then barrier
// broadcasts the guarantee to all waves.
#define WAITCNT_VM(N) asm volatile("s_waitcnt vmcnt(" #N ")" ::: "memory")
#define WAITCNT_LGKM0() do { \
    asm volatile("s_waitcnt lgkmcnt(0)" ::: "memory"); \
    __builtin_amdgcn_sched_barrier(0); \
} while (0)
#define RAW_BARRIER() __builtin_amdgcn_s_barrier()

// ---------------------------------------------------------------------------
// prep: split x and w into (hi,lo) bf16 pairs in one launch.
// ---------------------------------------------------------------------------
__global__ __launch_bounds__(256) void prep_kernel(const float4* __restrict__ x,
                                                   const float4* __restrict__ w,
                                                   u16x4* __restrict__ xhi, u16x4* __restrict__ xlo,
                                                   u16x4* __restrict__ whi, u16x4* __restrict__ wlo,
                                                   int n4x, int n4w)
{
    int i = blockIdx.x * 256 + threadIdx.x;
    const float4* src; u16x4 *hi, *lo; int idx;
    if (i < n4x) { src = x; hi = xhi; lo = xlo; idx = i; }
    else { idx = i - n4x; if (idx >= n4w) return; src = w; hi = whi; lo = wlo; }
    float4 v = src[idx];
    u16x4 h, l;
    h.x = f2bf(v.x); l.x = f2bf(v.x - bf2f(h.x));
    h.y = f2bf(v.y); l.y = f2bf(v.y - bf2f(h.y));
    h.z = f2bf(v.z); l.z = f2bf(v.z - bf2f(h.z));
    h.w = f2bf(v.w); l.w = f2bf(v.w - bf2f(h.w));
    hi[idx] = h; lo[idx] = l;
}

// fp32 -> bf16 (hi only), for fc_weight (runs after gemm1; dst aliases wlo)
__global__ __launch_bounds__(256) void cvt_bf16_kernel(const float4* __restrict__ src,
                                                       u16x4* __restrict__ dst, int n4)
{
    int i = blockIdx.x * 256 + threadIdx.x;
    if (i >= n4) return;
    float4 v = src[i];
    u16x4 h;
    h.x = f2bf(v.x); h.y = f2bf(v.y); h.z = f2bf(v.z); h.w = f2bf(v.w);
    dst[i] = h;
}

// ---------------------------------------------------------------------------
// GEMM1 (MFMA 32x32x16, split-bf16, fused) — best of 8 schedule variants
// (413-420 us, MfmaUtil ~47%): C = Xhi.Whi + Xhi.Wlo + Xlo.Whi + bias.
// 512 thr / 8 waves, BM=128 x BN=256, BK=32, triple-buffered LDS 144 KB,
// prefetch depth 2, per-phase interleave:
//   {8 ds_read(cur) ; 3 gload(tile t+2) ; s_barrier ; lgkmcnt(0)+sched_bar ;
//    setprio(1) ; 12 MFMA ; setprio(0) ; s_barrier}
// Counted vmcnt(6) once per K-tile; NEVER drains to 0 in the loop (R11's
// 4-phase dbuf variant with a drain-0 lost 100us — T4 rule confirmed again).
// Not HBM-bound (R13 swizzle: FETCH -41%, time +2%). Precision: 3 MFMA
// passes REQUIRED (cross-term omission -> ~0.3-knot interp position errors).
// ---------------------------------------------------------------------------
__global__ __launch_bounds__(512) void gemm1_mfma_fused_kernel(
        const unsigned short* __restrict__ xhi,
        const unsigned short* __restrict__ xlo,
        const unsigned short* __restrict__ whi,
        const unsigned short* __restrict__ wlo,
        const float* __restrict__ bias,
        float* __restrict__ C)
{
    __shared__ unsigned short sAh[3 * 128 * 32];   // 24 KB
    __shared__ unsigned short sAl[3 * 128 * 32];   // 24 KB
    __shared__ unsigned short sBh[3 * 256 * 32];   // 48 KB
    __shared__ unsigned short sBl[3 * 256 * 32];   // 48 KB

    const int tid  = threadIdx.x;    // 0..511
    const int lane = tid & 63;
    const int w    = tid >> 6;       // 0..7
    const int wm   = w & 1;          // m-half: rows wm*64 .. +64
    const int wn   = w >> 1;         // n-quarter: cols wn*64 .. +64
    const int m0   = blockIdx.y * 128;
    const int n0   = blockIdx.x * 256;

    // A staging: 512 chunks (128 rows x 4 chunks of 8 bf16); 1/thread
    const int ra = tid >> 2;
    const int qa = (tid & 3) ^ ((ra >> 1) & 3);
    const size_t a_goff = (size_t)(m0 + ra) * NDIM + qa * 8;
    const int a_lb = (w * 64) * 8;   // wave-uniform base (shorts)

    // B staging: 1024 chunks (256 rows x 4); 2/thread
    size_t b_goff[2]; int b_lb[2];
#pragma unroll
    for (int t = 0; t < 2; t++) {
        const int c = t * 512 + tid;
        const int r = c >> 2;
        const int q = (c & 3) ^ ((r >> 1) & 3);
        b_goff[t] = (size_t)(n0 + r) * NDIM + q * 8;
        b_lb[t]   = (t * 512 + w * 64) * 8;
    }

    // fragment read offsets: frag row r, logical k-chunk q = 2*ks + lk2
    const int ln32 = lane & 31;
    const int lk2  = lane >> 5;
    int offA[2][2], offB[2][2];   // [tile][kstep]
#pragma unroll
    for (int i = 0; i < 2; i++)
#pragma unroll
        for (int ks = 0; ks < 2; ks++) {
            const int rfa = wm * 64 + i * 32 + ln32;
            offA[i][ks] = rfa * 32 + (((2 * ks + lk2) ^ ((rfa >> 1) & 3)) * 8);
            const int rfb = wn * 64 + i * 32 + ln32;
            offB[i][ks] = rfb * 32 + (((2 * ks + lk2) ^ ((rfb >> 1) & 3)) * 8);
        }

    f32x16 acc[2][2];
#pragma unroll
    for (int i = 0; i < 2; i++)
#pragma unroll
        for (int j = 0; j < 2; j++)
#pragma unroll
            for (int r = 0; r < 16; r++) acc[i][j][r] = 0.f;

#define G1_STAGE_ALL(AOFF, BOFF, KT) do { \
    GLOAD_LDS(xhi + a_goff + (KT), &sAh[(AOFF) + a_lb]); \
    GLOAD_LDS(xlo + a_goff + (KT), &sAl[(AOFF) + a_lb]); \
    GLOAD_LDS(whi + b_goff[0] + (KT), &sBh[(BOFF) + b_lb[0]]); \
    GLOAD_LDS(whi + b_goff[1] + (KT), &sBh[(BOFF) + b_lb[1]]); \
    GLOAD_LDS(wlo + b_goff[0] + (KT), &sBl[(BOFF) + b_lb[0]]); \
    GLOAD_LDS(wlo + b_goff[1] + (KT), &sBl[(BOFF) + b_lb[1]]); \
} while (0)

    // prologue: tiles 0 and 1 into bufs 0 and 1 (12 loads in flight)
    G1_STAGE_ALL(0, 0, 0);
    G1_STAGE_ALL(4096, 8192, 32);
    WAITCNT_VM(6);               // tile 0 landed (tile 1's 6 stay in flight)
    RAW_BARRIER();

    int cA = 0, cB = 0;               // compute-buffer offsets (shorts)
    int sA = 2 * 4096, sB = 2 * 8192; // stage-buffer offsets (buf 2)

    for (int kt = 0; kt < NDIM; kt += 32) {
        const int skt = (kt + 64 < NDIM) ? kt + 64 : 0;   // dummy on last 2 iters

        // ---------------- phase 0 (ks = 0) ----------------
        {
            bf16x8 ah[2], al[2], bh[2], bl[2];
#pragma unroll
            for (int i = 0; i < 2; i++) {
                ah[i] = *(const bf16x8*)&sAh[cA + offA[i][0]];
                al[i] = *(const bf16x8*)&sAl[cA + offA[i][0]];
                bh[i] = *(const bf16x8*)&sBh[cB + offB[i][0]];
                bl[i] = *(const bf16x8*)&sBl[cB + offB[i][0]];
            }
            // first half of tile t+2 staging (3 loads)
            GLOAD_LDS(xhi + a_goff + skt, &sAh[sA + a_lb]);
            GLOAD_LDS(xlo + a_goff + skt, &sAl[sA + a_lb]);
            GLOAD_LDS(whi + b_goff[0] + skt, &sBh[sB + b_lb[0]]);
            RAW_BARRIER();
            WAITCNT_LGKM0();
            __builtin_amdgcn_s_setprio(1);
#pragma unroll
            for (int i = 0; i < 2; i++)
#pragma unroll
                for (int j = 0; j < 2; j++) {
                    acc[i][j] = __builtin_amdgcn_mfma_f32_32x32x16_bf16(ah[i], bh[j], acc[i][j], 0, 0, 0);
                    acc[i][j] = __builtin_amdgcn_mfma_f32_32x32x16_bf16(ah[i], bl[j], acc[i][j], 0, 0, 0);
                    acc[i][j] = __builtin_amdgcn_mfma_f32_32x32x16_bf16(al[i], bh[j], acc[i][j], 0, 0, 0);
                }
            __builtin_amdgcn_s_setprio(0);
            RAW_BARRIER();
        }

        // ---------------- phase 1 (ks = 1) ----------------
        {
            bf16x8 ah[2], al[2], bh[2], bl[2];
#pragma unroll
            for (int i = 0; i < 2; i++) {
                ah[i] = *(const bf16x8*)&sAh[cA + offA[i][1]];
                al[i] = *(const bf16x8*)&sAl[cA + offA[i][1]];
                bh[i] = *(const bf16x8*)&sBh[cB + offB[i][1]];
                bl[i] = *(const bf16x8*)&sBl[cB + offB[i][1]];
            }
            // second half of tile t+2 staging (3 loads)
            GLOAD_LDS(whi + b_goff[1] + skt, &sBh[sB + b_lb[1]]);
            GLOAD_LDS(wlo + b_goff[0] + skt, &sBl[sB + b_lb[0]]);
            GLOAD_LDS(wlo + b_goff[1] + skt, &sBl[sB + b_lb[1]]);
            WAITCNT_VM(6);           // tile t+1 landed; t+2's 6 stay in flight
            RAW_BARRIER();
            WAITCNT_LGKM0();
            __builtin_amdgcn_s_setprio(1);
#pragma unroll
            for (int i = 0; i < 2; i++)
#pragma unroll
                for (int j = 0; j < 2; j++) {
                    acc[i][j] = __builtin_amdgcn_mfma_f32_32x32x16_bf16(ah[i], bh[j], acc[i][j], 0, 0, 0);
                    acc[i][j] = __builtin_amdgcn_mfma_f32_32x32x16_bf16(ah[i], bl[j], acc[i][j], 0, 0, 0);
                    acc[i][j] = __builtin_amdgcn_mfma_f32_32x32x16_bf16(al[i], bh[j], acc[i][j], 0, 0, 0);
                }
            __builtin_amdgcn_s_setprio(0);
            RAW_BARRIER();
        }

        cA += 4096; if (cA == 12288) cA = 0;
        cB += 8192; if (cB == 24576) cB = 0;
        sA += 4096; if (sA == 12288) sA = 0;
        sB += 8192; if (sB == 24576) sB = 0;
    }

#undef G1_STAGE_ALL

    // epilogue: 32x32 C/D: col = lane&31, row = (reg&3)+8*(reg>>2)+4*(lane>>5)
    float bb[2];
#pragma unroll
    for (int j = 0; j < 2; j++) bb[j] = bias[n0 + wn * 64 + j * 32 + ln32];
#pragma unroll
    for (int i = 0; i < 2; i++) {
#pragma unroll
        for (int j = 0; j < 2; j++) {
            const int n = n0 + wn * 64 + j * 32 + ln32;
#pragma unroll
            for (int reg = 0; reg < 16; reg++) {
                const int m = m0 + wm * 64 + i * 32 + (reg & 3) + 8 * (reg >> 2) + 4 * lk2;
                C[(size_t)m * NDIM + n] = acc[i][j][reg] + bb[j];
            }
        }
    }
}

// ---------------------------------------------------------------------------
// Warp kernel: gamma = cumsum(softmax(row)); warped = interp(gamma, xs, x~).
// Reads x~ = xhi+xlo (L2/L3-warm from gemm1's sweeps; R8 showed cold fp32 x
// costs ~30us despite identical byte count). Padded s_x index i+(i>>5)
// breaks the interp-gather bank conflict. Writes warped bf16.
// Self-aliasing (Wout == xlo) safe: each thread overwrites only its own 16B.
// ---------------------------------------------------------------------------
#define SXI(i) ((i) + ((i) >> 5))

__global__ __launch_bounds__(256) void warp_bf16_kernel(const unsigned short* __restrict__ Xhi,
                                                        const unsigned short* __restrict__ Xlo,
                                                        const float* __restrict__ L,
                                                        unsigned short* __restrict__ Wout)
{
    const int N = NDIM;
    const int row = blockIdx.x;
    const int tid = threadIdx.x;
    const int lane = tid & 63;
    const int wave = tid >> 6;

    __shared__ float s_x[NDIM + NDIM / 32];   // padded: 1 extra per 32
    __shared__ float s_red[4];
    __shared__ float s_wsum[4];

    const float* lrow = L + (size_t)row * N;

    float v[8];
    {
        float4 l0 = *(const float4*)(lrow + tid * 8);
        float4 l1 = *(const float4*)(lrow + tid * 8 + 4);
        v[0] = l0.x; v[1] = l0.y; v[2] = l0.z; v[3] = l0.w;
        v[4] = l1.x; v[5] = l1.y; v[6] = l1.z; v[7] = l1.w;
        u16x8 hx = *(const u16x8*)(Xhi + (size_t)row * N + tid * 8);
        u16x8 lx = *(const u16x8*)(Xlo + (size_t)row * N + tid * 8);
        float xv[8];
#pragma unroll
        for (int j = 0; j < 8; j++) xv[j] = bf2f(hx[j]) + bf2f(lx[j]);
        const int sb = SXI(tid * 8);   // 8 consecutive slots share the shift
        *(float4*)&s_x[sb]     = make_float4(xv[0], xv[1], xv[2], xv[3]);
        *(float4*)&s_x[sb + 4] = make_float4(xv[4], xv[5], xv[6], xv[7]);
    }

    float mx = v[0];
#pragma unroll
    for (int j = 1; j < 8; j++) mx = fmaxf(mx, v[j]);
#pragma unroll
    for (int off = 32; off > 0; off >>= 1) mx = fmaxf(mx, __shfl_down(mx, off));
    if (lane == 0) s_red[wave] = mx;
    __syncthreads();
    mx = fmaxf(fmaxf(s_red[0], s_red[1]), fmaxf(s_red[2], s_red[3]));

    float c = 0.0f;
#pragma unroll
    for (int j = 0; j < 8; j++) {
        float e = __expf(v[j] - mx);
        c += e;
        v[j] = c;
    }

    float sc = c;
#pragma unroll
    for (int off = 1; off < 64; off <<= 1) {
        float t = __shfl_up(sc, off);
        if (lane >= off) sc += t;
    }
    if (lane == 63) s_wsum[wave] = sc;
    __syncthreads();
    float base = 0.0f, total = 0.0f;
#pragma unroll
    for (int w = 0; w < 4; w++) {
        float t = s_wsum[w];
        if (w < wave) base += t;
        total += t;
    }
    const float inv = 1.0f / total;
    const float prefix = base + (sc - c);

    u16x8 o;
#pragma unroll
    for (int j = 0; j < 8; j++) {
        float g = (prefix + v[j]) * inv;
        float pos = g * (float)(N - 1);
        pos = fminf(fmaxf(pos, 0.0f), (float)(N - 1));
        int i = (int)pos;
        if (i > N - 2) i = N - 2;
        float f = pos - (float)i;
        float x0 = s_x[SXI(i)];
        float x1 = s_x[SXI(i + 1)];
        o[j] = f2bf(fmaf(f, x1 - x0, x0));
    }
    *(u16x8*)(Wout + (size_t)row * N + tid * 8) = o;
}

// ---------------------------------------------------------------------------
// GEMM2 (MFMA bf16) — proven best:
// out[m][n] = sum_k Wp[m][k]*F[n][k] + fb[n]  (n<100)
// BM=32 (grid 512 -> 2 blocks/CU), BN=128 (rows>=100 clamped), 4 waves each
// owning 32x32. LDS 40 KB double-buffered; counted vmcnt(5).
// ---------------------------------------------------------------------------
__global__ __launch_bounds__(256) void gemm2_mfma_kernel(
        const unsigned short* __restrict__ Wp,   // warped bf16 [16384][2048]
        const unsigned short* __restrict__ F,    // fc bf16 [100][2048]
        const float* __restrict__ fb,
        float* __restrict__ out)
{
    __shared__ unsigned short sA[2 * 32 * 64];    // 8 KB, [r][q'] 8 chunks/row
    __shared__ unsigned short sB[2 * 128 * 64];   // 32 KB

    const int tid  = threadIdx.x;
    const int lane = tid & 63;
    const int w    = tid >> 6;   // wave owns n-strip w*32 .. +32
    const int m0   = blockIdx.x * 32;

    // A staging: 256 chunks (32 rows x 8), 1/thread; lane order = r*8+q
    const int ar = tid >> 3, aq = tid & 7;
    const size_t a_goff = (size_t)(m0 + ar) * NDIM + ((aq ^ (ar & 7)) * 8);
    const int a_lb = (w * 64) * 8;   // wave-uniform base (shorts)

    // B staging: 1024 chunks (128 rows x 8), 4/thread; fc row clamped to 99
    size_t b_goff[4]; int b_lb[4];
#pragma unroll
    for (int t = 0; t < 4; t++) {
        const int c = t * 256 + tid;
        const int r = c >> 3, q = c & 7;
        b_goff[t] = (size_t)(r < NCLS ? r : NCLS - 1) * NDIM + ((q ^ (r & 7)) * 8);
        b_lb[t]   = (t * 256 + w * 64) * 8;
    }

    // fragment offsets (16x16x32): logical k-chunk = ks*4 + (lane>>4)
    const int lm = lane & 15;
    const int lk = lane >> 4;
    int offA[2][2], offB[2][2];
#pragma unroll
    for (int i = 0; i < 2; i++)
#pragma unroll
        for (int ks = 0; ks < 2; ks++) {
            const int r = i * 16 + lm;                 // A rows 0..31 (all waves)
            offA[i][ks] = (r * 8 + ((ks * 4 + lk) ^ (r & 7))) * 8;
            const int rb = w * 32 + i * 16 + lm;       // B rows per wave strip
            offB[i][ks] = (rb * 8 + ((ks * 4 + lk) ^ (rb & 7))) * 8;
        }

    f32x4 acc[2][2];
#pragma unroll
    for (int i = 0; i < 2; i++)
#pragma unroll
        for (int j = 0; j < 2; j++) acc[i][j] = (f32x4){0.f, 0.f, 0.f, 0.f};

#define G2_STAGE(B, KT) do { \
    GLOAD_LDS(Wp + a_goff + (KT), &sA[(B) * 2048 + a_lb]); \
    _Pragma("unroll") \
    for (int t = 0; t < 4; t++) GLOAD_LDS(F + b_goff[t] + (KT), &sB[(B) * 8192 + b_lb[t]]); \
} while (0)

#define G2_COMPUTE(B) do { \
    _Pragma("unroll") \
    for (int ks = 0; ks < 2; ks++) { \
        bf16x8 af[2], bfr[2]; \
        _Pragma("unroll") \
        for (int i = 0; i < 2; i++) { \
            af[i]  = *(const bf16x8*)&sA[(B) * 2048 + offA[i][ks]]; \
            bfr[i] = *(const bf16x8*)&sB[(B) * 8192 + offB[i][ks]]; \
        } \
        _Pragma("unroll") \
        for (int i = 0; i < 2; i++) \
            _Pragma("unroll") \
            for (int j = 0; j < 2; j++) \
                acc[i][j] = __builtin_amdgcn_mfma_f32_16x16x32_bf16(af[i], bfr[j], acc[i][j], 0, 0, 0); \
    } \
} while (0)

    G2_STAGE(0, 0);   // 5 loads in flight

    for (int kt = 0; kt < NDIM; kt += 128) {
        G2_STAGE(1, kt + 64);            // +5 (kt+64 <= 1984, always valid)
        WAITCNT_VM(5);                   // buf0's 5 landed; buf1's stay in flight
        RAW_BARRIER();
        G2_COMPUTE(0);
        RAW_BARRIER();
        G2_STAGE(0, (kt + 128 < NDIM) ? kt + 128 : 0);   // dummy on last iter
        WAITCNT_VM(5);
        RAW_BARRIER();
        G2_COMPUTE(1);
        RAW_BARRIER();
    }

#undef G2_STAGE
#undef G2_COMPUTE

    const int cn = lane & 15;
    const int rg = lane >> 4;
#pragma unroll
    for (int i = 0; i < 2; i++) {
#pragma unroll
        for (int j = 0; j < 2; j++) {
            const int n = w * 32 + j * 16 + cn;
            if (n < NCLS) {
                const float bbn = fb[n];
#pragma unroll
                for (int reg = 0; reg < 4; reg++) {
                    const int m = m0 + i * 16 + rg * 4 + reg;
                    out[(size_t)m * NCLS + n] = acc[i][j][reg] + bbn;
                }
            }
        }
    }
}

// ---------------------------------------------------------------------------
// fp32 fallback path (only if ws_size too small) — proven R1 kernels.
// ---------------------------------------------------------------------------
__global__ __launch_bounds__(256) void gemm1_kernel(const float* __restrict__ X,
                                                    const float* __restrict__ W,
                                                    const float* __restrict__ bias,
                                                    float* __restrict__ C)
{
    const int K = NDIM;
    __shared__ float sA[16][128];
    __shared__ float sB[16][128];
    const int tid = threadIdx.x;
    const int tx = tid & 15;
    const int ty = tid >> 4;
    const int m0 = blockIdx.y * 128;
    const int n0 = blockIdx.x * 128;
    float acc[8][8];
#pragma unroll
    for (int i = 0; i < 8; i++)
#pragma unroll
        for (int j = 0; j < 8; j++) acc[i][j] = 0.0f;
    const int s_m = tid >> 1;
    const int s_c = (tid & 1) * 8;
    const float* Ag = X + (size_t)(m0 + s_m) * K + s_c;
    const float* Bg = W + (size_t)(n0 + s_m) * K + s_c;
    for (int kt = 0; kt < K; kt += 16) {
        float4 av0 = *(const float4*)(Ag + kt);
        float4 av1 = *(const float4*)(Ag + kt + 4);
        float4 bv0 = *(const float4*)(Bg + kt);
        float4 bv1 = *(const float4*)(Bg + kt + 4);
        __syncthreads();
        sA[s_c + 0][s_m] = av0.x; sA[s_c + 1][s_m] = av0.y;
        sA[s_c + 2][s_m] = av0.z; sA[s_c + 3][s_m] = av0.w;
        sA[s_c + 4][s_m] = av1.x; sA[s_c + 5][s_m] = av1.y;
        sA[s_c + 6][s_m] = av1.z; sA[s_c + 7][s_m] = av1.w;
        sB[s_c + 0][s_m] = bv0.x; sB[s_c + 1][s_m] = bv0.y;
        sB[s_c + 2][s_m] = bv0.z; sB[s_c + 3][s_m] = bv0.w;
        sB[s_c + 4][s_m] = bv1.x; sB[s_c + 5][s_m] = bv1.y;
        sB[s_c + 6][s_m] = bv1.z; sB[s_c + 7][s_m] = bv1.w;
        __syncthreads();
#pragma unroll
        for (int k = 0; k < 16; k++) {
            float4 a0 = *(const float4*)&sA[k][ty * 8];
            float4 a1 = *(const float4*)&sA[k][ty * 8 + 4];
            float4 b0 = *(const float4*)&sB[k][tx * 8];
            float4 b1 = *(const float4*)&sB[k][tx * 8 + 4];
            float a[8] = {a0.x, a0.y, a0.z, a0.w, a1.x, a1.y, a1.z, a1.w};
            float b[8] = {b0.x, b0.y, b0.z, b0.w, b1.x, b1.y, b1.z, b1.w};
#pragma unroll
            for (int i = 0; i < 8; i++)
#pragma unroll
                for (int j = 0; j < 8; j++)
                    acc[i][j] = fmaf(a[i], b[j], acc[i][j]);
        }
    }
    float bb[8];
#pragma unroll
    for (int j = 0; j < 8; j++) bb[j] = bias[n0 + tx * 8 + j];
#pragma unroll
    for (int i = 0; i < 8; i++) {
        const int m = m0 + ty * 8 + i;
        float* crow = C + (size_t)m * NDIM + n0 + tx * 8;
        *(float4*)(crow)     = make_float4(acc[i][0] + bb[0], acc[i][1] + bb[1],
                                           acc[i][2] + bb[2], acc[i][3] + bb[3]);
        *(float4*)(crow + 4) = make_float4(acc[i][4] + bb[4], acc[i][5] + bb[5],
                                           acc[i][6] + bb[6], acc[i][7] + bb[7]);
    }
}

__global__ __launch_bounds__(256) void warp_kernel_f32(const float* __restrict__ X,
                                                       float* __restrict__ L)
{
    const int N = NDIM;
    const int row = blockIdx.x;
    const int tid = threadIdx.x;
    const int lane = tid & 63;
    const int wave = tid >> 6;
    __shared__ float s_x[NDIM];
    __shared__ float s_red[4];
    __shared__ float s_wsum[4];
    float* lrow = L + (size_t)row * N;
    const float* xrow = X + (size_t)row * N;
    float v[8];
    {
        float4 l0 = *(const float4*)(lrow + tid * 8);
        float4 l1 = *(const float4*)(lrow + tid * 8 + 4);
        v[0] = l0.x; v[1] = l0.y; v[2] = l0.z; v[3] = l0.w;
        v[4] = l1.x; v[5] = l1.y; v[6] = l1.z; v[7] = l1.w;
        float4 x0 = *(const float4*)(xrow + tid * 8);
        float4 x1 = *(const float4*)(xrow + tid * 8 + 4);
        *(float4*)&s_x[tid * 8]     = x0;
        *(float4*)&s_x[tid * 8 + 4] = x1;
    }
    float mx = v[0];
#pragma unroll
    for (int j = 1; j < 8; j++) mx = fmaxf(mx, v[j]);
#pragma unroll
    for (int off = 32; off > 0; off >>= 1) mx = fmaxf(mx, __shfl_down(mx, off));
    if (lane == 0) s_red[wave] = mx;
    __syncthreads();
    mx = fmaxf(fmaxf(s_red[0], s_red[1]), fmaxf(s_red[2], s_red[3]));
    float c = 0.0f;
#pragma unroll
    for (int j = 0; j < 8; j++) {
        float e = __expf(v[j] - mx);
        c += e;
        v[j] = c;
    }
    float sc = c;
#pragma unroll
    for (int off = 1; off < 64; off <<= 1) {
        float t = __shfl_up(sc, off);
        if (lane >= off) sc += t;
    }
    if (lane == 63) s_wsum[wave] = sc;
    __syncthreads();
    float base = 0.0f, total = 0.0f;
#pragma unroll
    for (int w = 0; w < 4; w++) {
        float t = s_wsum[w];
        if (w < wave) base += t;
        total += t;
    }
    const float inv = 1.0f / total;
    const float prefix = base + (sc - c);
    float w8[8];
#pragma unroll
    for (int j = 0; j < 8; j++) {
        float g = (prefix + v[j]) * inv;
        float pos = g * (float)(N - 1);
        pos = fminf(fmaxf(pos, 0.0f), (float)(N - 1));
        int i = (int)pos;
        if (i > N - 2) i = N - 2;
        float f = pos - (float)i;
        w8[j] = fmaf(f, s_x[i + 1] - s_x[i], s_x[i]);
    }
    *(float4*)(lrow + tid * 8)     = make_float4(w8[0], w8[1], w8[2], w8[3]);
    *(float4*)(lrow + tid * 8 + 4) = make_float4(w8[4], w8[5], w8[6], w8[7]);
}

__global__ __launch_bounds__(256) void gemm2_kernel(const float* __restrict__ Wp,
                                                    const float* __restrict__ F,
                                                    const float* __restrict__ fb,
                                                    float* __restrict__ out)
{
    const int K = NDIM;
    __shared__ float sA[16][64];
    __shared__ float sB[16][128];
    const int tid = threadIdx.x;
    const int tx = tid & 15;
    const int ty = tid >> 4;
    const int m0 = blockIdx.x * 64;
    float acc[4][8];
#pragma unroll
    for (int i = 0; i < 4; i++)
#pragma unroll
        for (int j = 0; j < 8; j++) acc[i][j] = 0.0f;
    const int a_m = tid >> 2;
    const int a_c = (tid & 3) * 4;
    const int b_n = tid >> 1;
    const int b_c = (tid & 1) * 8;
    const bool bvalid = (b_n < NCLS);
    const float* Ag = Wp + (size_t)(m0 + a_m) * K + a_c;
    const float* Bg = F + (size_t)b_n * K + b_c;
    for (int kt = 0; kt < K; kt += 16) {
        float4 av = *(const float4*)(Ag + kt);
        float4 bv0 = make_float4(0.f, 0.f, 0.f, 0.f);
        float4 bv1 = make_float4(0.f, 0.f, 0.f, 0.f);
        if (bvalid) {
            bv0 = *(const float4*)(Bg + kt);
            bv1 = *(const float4*)(Bg + kt + 4);
        }
        __syncthreads();
        sA[a_c + 0][a_m] = av.x; sA[a_c + 1][a_m] = av.y;
        sA[a_c + 2][a_m] = av.z; sA[a_c + 3][a_m] = av.w;
        sB[b_c + 0][b_n] = bv0.x; sB[b_c + 1][b_n] = bv0.y;
        sB[b_c + 2][b_n] = bv0.z; sB[b_c + 3][b_n] = bv0.w;
        sB[b_c + 4][b_n] = bv1.x; sB[b_c + 5][b_n] = bv1.y;
        sB[b_c + 6][b_n] = bv1.z; sB[b_c + 7][b_n] = bv1.w;
        __syncthreads();
#pragma unroll
        for (int k = 0; k < 16; k++) {
            float4 a4 = *(const float4*)&sA[k][ty * 4];
            float4 b0 = *(const float4*)&sB[k][tx * 8];
            float4 b1 = *(const float4*)&sB[k][tx * 8 + 4];
            float a[4] = {a4.x, a4.y, a4.z, a4.w};
            float b[8] = {b0.x, b0.y, b0.z, b0.w, b1.x, b1.y, b1.z, b1.w};
#pragma unroll
            for (int i = 0; i < 4; i++)
#pragma unroll
                for (int j = 0; j < 8; j++)
                    acc[i][j] = fmaf(a[i], b[j], acc[i][j]);
        }
    }
#pragma unroll
    for (int i = 0; i < 4; i++) {
        const int m = m0 + ty * 4 + i;
#pragma unroll
        for (int j = 0; j < 8; j++) {
            const int n = tx * 8 + j;
            if (n < NCLS) out[(size_t)m * NCLS + n] = acc[i][j] + fb[n];
        }
    }
}

extern "C" void kernel_launch(void* const* d_in, const int* in_sizes, int n_in,
                              void* d_out, int out_size, void* d_ws, size_t ws_size,
                              hipStream_t stream) {
    const float* x  = (const float*)d_in[0];   // time_series [16384,2048]
    const float* ww = (const float*)d_in[1];   // w_weight [2048,2048]
    const float* wb = (const float*)d_in[2];   // w_bias [2048]
    const float* fw = (const float*)d_in[3];   // fc_weight [100,2048]
    const float* fb = (const float*)d_in[4];   // fc_bias [100]
    float* out = (float*)d_out;                // [16384,100]

    char* ws = (char*)d_ws;
    float* logits = (float*)ws;                                   // 128 MiB fp32
    const size_t LOGITS_B = (size_t)BROWS * NDIM * 4;             // 134217728
    const size_t XBF_B    = (size_t)BROWS * NDIM * 2;             // 67108864
    const size_t WBF_B    = (size_t)NDIM * NDIM * 2;              // 8388608
    unsigned short* xhi = (unsigned short*)(ws + LOGITS_B);
    unsigned short* xlo = (unsigned short*)(ws + LOGITS_B + XBF_B);
    unsigned short* whi = (unsigned short*)(ws + LOGITS_B + 2 * XBF_B);
    unsigned short* wlo = (unsigned short*)(ws + LOGITS_B + 2 * XBF_B + WBF_B);
    // aliases (dead after gemm1): warped bf16 reuses xlo; fc bf16 reuses wlo
    unsigned short* wbf = xlo;
    unsigned short* fwb = wlo;
    const size_t WS_NEED = LOGITS_B + 2 * XBF_B + 2 * WBF_B;      // 285212672

    if (ws_size >= WS_NEED) {
        const int n4x = BROWS * NDIM / 4;   // 8388608
        const int n4w = NDIM * NDIM / 4;    // 1048576
        prep_kernel<<<(n4x + n4w + 255) / 256, 256, 0, stream>>>(
            (const float4*)x, (const float4*)ww,
            (u16x4*)xhi, (u16x4*)xlo, (u16x4*)whi, (u16x4*)wlo, n4x, n4w);
        gemm1_mfma_fused_kernel<<<dim3(NDIM / 256, BROWS / 128), 512, 0, stream>>>(
            xhi, xlo, whi, wlo, wb, logits);
        warp_bf16_kernel<<<BROWS, 256, 0, stream>>>(xhi, xlo, logits, wbf);
        cvt_bf16_kernel<<<(NCLS * NDIM / 4 + 255) / 256, 256, 0, stream>>>(
            (const float4*)fw, (u16x4*)fwb, NCLS * NDIM / 4);
        gemm2_mfma_kernel<<<BROWS / 32, 256, 0, stream>>>(wbf, fwb, fb, out);
    } else {
        gemm1_kernel<<<dim3(NDIM / 128, BROWS / 128), 256, 0, stream>>>(x, ww, wb, logits);
        warp_kernel_f32<<<BROWS, 256, 0, stream>>>(x, logits);
        gemm2_kernel<<<BROWS / 64, 256, 0, stream>>>(logits, fw, fb, out);
    }
}